// Round 2
// baseline (275.721 us; speedup 1.0000x reference)
//
#include <hip/hip_runtime.h>

typedef __attribute__((ext_vector_type(8))) short bf16x8;
typedef __attribute__((ext_vector_type(4))) float f32x4;

#define GLOAD_LDS16(gp, lp)                                                   \
  __builtin_amdgcn_global_load_lds(                                           \
      (const __attribute__((address_space(1))) void*)(gp),                    \
      (__attribute__((address_space(3))) void*)(lp), 16, 0, 0)

__device__ inline unsigned short f2bf(float f) {
  union { float f; unsigned u; } a; a.f = f;
  unsigned u = a.u;
  return (unsigned short)((u + 0x7fffu + ((u >> 16) & 1u)) >> 16);  // RNE
}

__global__ void cvt_f32_bf16(const float* __restrict__ in,
                             unsigned short* __restrict__ out, int n4) {
  int i = blockIdx.x * blockDim.x + threadIdx.x;
  int stride = gridDim.x * blockDim.x;
  for (; i < n4; i += stride) {
    float4 v = reinterpret_cast<const float4*>(in)[i];
    ushort4 o;
    o.x = f2bf(v.x); o.y = f2bf(v.y); o.z = f2bf(v.z); o.w = f2bf(v.w);
    reinterpret_cast<ushort4*>(out)[i] = o;
  }
}

// Implicit GEMM, 8-phase schedule (T3+T4+T5): M=123008, N=256, K=1152.
// BM=256, BN=256, BK=64 (2 K=32 halves), 512 thr (2x4 waves, 128x64/wave).
// LDS 128KB: buf{0,1} x { A-Klo, A-Khi, B-Klo, B-Khi } x 16KB.
// Counted vmcnt(6) at phases 4/8 only; 2 raw s_barrier per phase; setprio
// around MFMA cluster. Source-side XOR swizzle (seg ^= (row>>1)&3).
#define M_TOT 123008

// tile tau (0..17): tap = tau>>1 (0..8), chb = (tau&1)*64
#define OFFS(tau, oA, oB) do {                                                \
    int _tap = (tau) >> 1; int _kh = (_tap * 11) >> 5; int _kw = _tap - _kh * 3; \
    oA = (_kh * 64 + _kw) * 128 + ((tau) & 1) * 64;                           \
    oB = _tap * 128 + ((tau) & 1) * 64;                                       \
  } while (0)

__global__ __launch_bounds__(512, 2) void conv_gemm(
    const unsigned short* __restrict__ A,   // bf16 input NHWC (32,64,64,128)
    const unsigned short* __restrict__ Bw,  // bf16 w (256,1152) == B^T
    const float* __restrict__ bias,         // fp32 (256)
    float* __restrict__ out)                // fp32 (123008,256)
{
  __shared__ char lds[131072] __attribute__((aligned(16)));

  const int tid = threadIdx.x;
  const int bm = blockIdx.x;

  // ---- staging source coords: seg o=tid -> (row=o>>2, s'=o&3); 2nd load +512
  const int r0 = tid >> 2;                          // 0..127
  const int sp = (tid & 3) ^ ((tid >> 3) & 3);      // swizzled 16B segment
  int m0 = bm * 256 + r0;        if (m0 > M_TOT - 1) m0 = M_TOT - 1;
  int m1 = bm * 256 + r0 + 128;  if (m1 > M_TOT - 1) m1 = M_TOT - 1;
  int n0 = m0 / 3844, rem0 = m0 % 3844;
  int n1 = m1 / 3844, rem1 = m1 % 3844;
  const int p0 = (n0 * 64 + rem0 / 62) * 64 + rem0 % 62;
  const int p1 = (n1 * 64 + rem1 / 62) * 64 + rem1 % 62;
  const int gA0 = p0 * 128 + sp * 8;                // element offsets
  const int gA1 = p1 * 128 + sp * 8;
  const int gB0 = r0 * 1152 + sp * 8;
  const int gB1 = gB0 + 128 * 1152;

  // ---- ds-read fragment bases ----
  const int lane = tid & 63, wv = tid >> 6;
  const int wm = wv >> 2, wn = wv & 3;              // 2x4 wave grid
  const int l15 = lane & 15, s = lane >> 4;
  const int rbA = wm * 128 + l15;
  const int pA = rbA * 64 + ((s ^ ((rbA >> 1) & 3)) * 16);
  const int rbB = wn * 64 + l15;
  const int pB = 32768 + rbB * 64 + ((s ^ ((rbB >> 1) & 3)) * 16);

#define LDSA(bufp, i_, kk)                                                    \
  (*reinterpret_cast<const bf16x8*>(lds + (bufp) * 65536 + (kk) * 16384 + pA + (i_) * 1024))
#define LDSB(bufp, j_, kk)                                                    \
  (*reinterpret_cast<const bf16x8*>(lds + (bufp) * 65536 + (kk) * 16384 + pB + (j_) * 1024))

#define STAGE_A(bufp, kk, offA) do {                                          \
    GLOAD_LDS16(A + gA0 + (offA) + (kk) * 32,                                 \
                lds + (bufp) * 65536 + (kk) * 16384 + tid * 16);              \
    GLOAD_LDS16(A + gA1 + (offA) + (kk) * 32,                                 \
                lds + (bufp) * 65536 + (kk) * 16384 + (tid + 512) * 16);      \
  } while (0)
#define STAGE_B(bufp, kk, offB) do {                                          \
    GLOAD_LDS16(Bw + gB0 + (offB) + (kk) * 32,                                \
                lds + (bufp) * 65536 + 32768 + (kk) * 16384 + tid * 16);      \
    GLOAD_LDS16(Bw + gB1 + (offB) + (kk) * 32,                                \
                lds + (bufp) * 65536 + 32768 + (kk) * 16384 + (tid + 512) * 16); \
  } while (0)

  f32x4 acc[8][4];
  #pragma unroll
  for (int i = 0; i < 8; ++i)
    #pragma unroll
    for (int j = 0; j < 4; ++j)
      acc[i][j] = (f32x4){0.f, 0.f, 0.f, 0.f};

  bf16x8 bk[4];

  // phase: [ds reads][stage 1 half-tile][fence?] bar; MFMA x16 (setprio); bar
#define PHASE(bufp, kk, rbase, readb, STAGE_STMT, dofence) do {               \
    bf16x8 af[4];                                                             \
    if (readb) {                                                              \
      _Pragma("unroll") for (int j = 0; j < 4; ++j) bk[j] = LDSB(bufp, j, kk);\
    }                                                                         \
    _Pragma("unroll") for (int ii = 0; ii < 4; ++ii)                          \
      af[ii] = LDSA(bufp, (rbase) + ii, kk);                                  \
    STAGE_STMT;                                                               \
    if (dofence) {                                                            \
      asm volatile("s_waitcnt vmcnt(6)" ::: "memory");                        \
      __builtin_amdgcn_sched_barrier(0);                                      \
    }                                                                         \
    __builtin_amdgcn_s_barrier();                                             \
    __builtin_amdgcn_s_setprio(1);                                            \
    _Pragma("unroll") for (int ii = 0; ii < 4; ++ii)                          \
      _Pragma("unroll") for (int j = 0; j < 4; ++j)                           \
        acc[(rbase) + ii][j] = __builtin_amdgcn_mfma_f32_16x16x32_bf16(       \
            af[ii], bk[j], acc[(rbase) + ii][j], 0, 0, 0);                    \
    __builtin_amdgcn_s_setprio(0);                                            \
    __builtin_amdgcn_s_barrier();                                             \
    if (dofence) __builtin_amdgcn_sched_barrier(0);                           \
  } while (0)

  // ---- prologue: tile0 fully + 3 half-tiles of tile1; oldest-first order ----
  {
    int oA0, oB0, oA1, oB1;
    OFFS(0, oA0, oB0); OFFS(1, oA1, oB1);
    STAGE_B(0, 0, oB0); STAGE_A(0, 0, oA0); STAGE_B(0, 1, oB0); STAGE_A(0, 1, oA0);
    STAGE_B(1, 0, oB1); STAGE_A(1, 0, oA1); STAGE_B(1, 1, oB1);
    asm volatile("s_waitcnt vmcnt(6)" ::: "memory");
    __builtin_amdgcn_s_barrier();
    __builtin_amdgcn_sched_barrier(0);
  }

  // ---- main loop: 9 iterations x 2 K-tiles; stage roles fixed per phase ----
  #pragma unroll 1
  for (int it = 0; it < 9; ++it) {
    const int t1 = 2 * it + 1;
    const int t2 = (2 * it + 2 > 17) ? 17 : 2 * it + 2;   // K-tail clamp
    const int t3 = (2 * it + 3 > 17) ? 17 : 2 * it + 3;
    int oA1, oB1, oA2, oB2, oA3, oB3;
    OFFS(t1, oA1, oB1); OFFS(t2, oA2, oB2); OFFS(t3, oA3, oB3);

    PHASE(0, 0, 0, 1, STAGE_A(1, 1, oA1), 0);   // P1: stage (t+1).A-Khi
    PHASE(0, 0, 4, 0, STAGE_B(0, 0, oB2), 0);   // P2: stage (t+2).B-Klo
    PHASE(0, 1, 0, 1, STAGE_A(0, 0, oA2), 0);   // P3: stage (t+2).A-Klo
    PHASE(0, 1, 4, 0, STAGE_B(0, 1, oB2), 1);   // P4: stage (t+2).B-Khi + fence
    PHASE(1, 0, 0, 1, STAGE_A(0, 1, oA2), 0);   // P5: stage (t+2).A-Khi
    PHASE(1, 0, 4, 0, STAGE_B(1, 0, oB3), 0);   // P6: stage (t+3).B-Klo
    PHASE(1, 1, 0, 1, STAGE_A(1, 0, oA3), 0);   // P7: stage (t+3).A-Klo
    PHASE(1, 1, 4, 0, STAGE_B(1, 1, oB3), 1);   // P8: stage (t+3).B-Khi + fence
  }

  // ---- epilogue: bias + fp32 store; C/D: col=lane&15, row=(lane>>4)*4+r ----
  const int colb = wn * 64 + l15;
  const int rbase = bm * 256 + wm * 128 + s * 4;
  if (bm != 480) {
    #pragma unroll
    for (int j = 0; j < 4; ++j) {
      const float bv = bias[colb + j * 16];
      #pragma unroll
      for (int ii = 0; ii < 8; ++ii) {
        #pragma unroll
        for (int r = 0; r < 4; ++r)
          out[(size_t)(rbase + ii * 16 + r) * 256 + colb + j * 16] = acc[ii][j][r] + bv;
      }
    }
  } else {
    #pragma unroll
    for (int j = 0; j < 4; ++j) {
      const float bv = bias[colb + j * 16];
      #pragma unroll
      for (int ii = 0; ii < 8; ++ii) {
        #pragma unroll
        for (int r = 0; r < 4; ++r) {
          const int row = rbase + ii * 16 + r;
          if (row < M_TOT)
            out[(size_t)row * 256 + colb + j * 16] = acc[ii][j][r] + bv;
        }
      }
    }
  }
}

extern "C" void kernel_launch(void* const* d_in, const int* in_sizes, int n_in,
                              void* d_out, int out_size, void* d_ws, size_t ws_size,
                              hipStream_t stream) {
  const float* inp = (const float*)d_in[0];   // (32,64,64,128) fp32
  const float* w   = (const float*)d_in[1];   // (256,1152) fp32
  const float* b   = (const float*)d_in[2];   // (256) fp32
  float* out = (float*)d_out;                 // (123008,256) fp32

  unsigned short* wsA = (unsigned short*)d_ws;          // bf16 input copy
  unsigned short* wsB = wsA + 16777216;                 // bf16 weight copy

  cvt_f32_bf16<<<2048, 256, 0, stream>>>(inp, wsA, 16777216 / 4);
  cvt_f32_bf16<<<288, 256, 0, stream>>>(w, wsB, 294912 / 4);
  conv_gemm<<<481, 512, 0, stream>>>(wsA, wsB, b, out);
}

// Round 4
// 267.045 us; speedup vs baseline: 1.0325x; 1.0325x over previous
//
#include <hip/hip_runtime.h>

typedef __attribute__((ext_vector_type(8))) short bf16x8;
typedef __attribute__((ext_vector_type(4))) float f32x4;

#define GLOAD_LDS16(gp, lp)                                                   \
  __builtin_amdgcn_global_load_lds(                                           \
      (const __attribute__((address_space(1))) void*)(gp),                    \
      (__attribute__((address_space(3))) void*)(lp), 16, 0, 0)

__device__ inline unsigned short f2bf(float f) {
  union { float f; unsigned u; } a; a.f = f;
  unsigned u = a.u;
  return (unsigned short)((u + 0x7fffu + ((u >> 16) & 1u)) >> 16);  // RNE
}

__global__ void cvt_f32_bf16(const float* __restrict__ in,
                             unsigned short* __restrict__ out, int n4) {
  int i = blockIdx.x * blockDim.x + threadIdx.x;
  int stride = gridDim.x * blockDim.x;
  for (; i < n4; i += stride) {
    float4 v = reinterpret_cast<const float4*>(in)[i];
    ushort4 o;
    o.x = f2bf(v.x); o.y = f2bf(v.y); o.z = f2bf(v.z); o.w = f2bf(v.w);
    reinterpret_cast<ushort4*>(out)[i] = o;
  }
}

// Repack w (256,1152) fp32 -> fragment-major bf16 B'. Unit (frag, lane) of
// 8 elems: frag = tau32*16 + fgrp; row = fgrp*16 + (lane&15);
// k = tau32*32 + (lane>>4)*8 + e. A wave's MFMA B-fragment (rows fgrp*16..+15,
// one K32 slice) is then one coalesced 1KB load.
__global__ void prep_B(const float* __restrict__ w,
                       unsigned short* __restrict__ Bp) {
  const int id = blockIdx.x * blockDim.x + threadIdx.x;  // 144*256 = 36864
  const int lane = id & 63, frag = id >> 6;
  const int tau32 = frag >> 4, fgrp = frag & 15;
  const int row = fgrp * 16 + (lane & 15);
  const int k0 = tau32 * 32 + ((lane >> 4) << 3);
  const float* src = w + row * 1152 + k0;
  float4 v0 = reinterpret_cast<const float4*>(src)[0];
  float4 v1 = reinterpret_cast<const float4*>(src)[1];
  ushort4 o0, o1;
  o0.x = f2bf(v0.x); o0.y = f2bf(v0.y); o0.z = f2bf(v0.z); o0.w = f2bf(v0.w);
  o1.x = f2bf(v1.x); o1.y = f2bf(v1.y); o1.z = f2bf(v1.z); o1.w = f2bf(v1.w);
  reinterpret_cast<ushort4*>(Bp)[id * 2] = o0;
  reinterpret_cast<ushort4*>(Bp)[id * 2 + 1] = o1;
}

// Implicit GEMM: M=123008=961*128 (exact), N=256, K=1152 (9 taps x 128 ch).
// 256 thr (4 waves, each owns 128x64 of C). A-only LDS (2x16KB dbuf -> 2
// blocks/CU); B' prefetched to VGPRs via plain coalesced loads (compiler
// inserts dependence-exact vmcnt waits at use). Manual counted fence
// vmcnt(20) covers only gload_lds->ds_read visibility: phase order is
// [STAGE_A(4) BPRE(8)] so prev phase's A-stages are the oldest 4 of 24
// outstanding. K-tile tau = k/64 (tap = tau>>1, chb = (tau&1)*64).
__global__ __launch_bounds__(256, 2) void conv_gemm(
    const unsigned short* __restrict__ A,   // bf16 NHWC (32,64,64,128)
    const unsigned short* __restrict__ Bp,  // bf16 fragment-major B'
    const float* __restrict__ bias,         // fp32 (256)
    float* __restrict__ out)                // fp32 (123008,256)
{
  __shared__ char lds[32768] __attribute__((aligned(16)));
  const int tid = threadIdx.x;

  // bijective XCD swizzle, grid 961 = 8*120 + 1
  const int bid = blockIdx.x;
  const int xcd = bid & 7, idx = bid >> 3;
  const int bm = (xcd == 0) ? idx : (121 + (xcd - 1) * 120 + idx);

  // ---- A staging: thread stages rows {srow, srow+64} x {kk0,kk1} ----
  const int srow = tid >> 2;                        // 0..63
  const int sp = (tid & 3) ^ ((tid >> 3) & 3);      // src-side XOR swizzle
  const int m0 = bm * 128 + srow;
  const int m1 = m0 + 64;
  const int n0 = m0 / 3844, q0 = m0 % 3844;
  const int n1 = m1 / 3844, q1 = m1 % 3844;
  const int p_lo = (n0 * 64 + q0 / 62) * 64 + q0 % 62;
  const int p_hi = (n1 * 64 + q1 / 62) * 64 + q1 % 62;

  // LDS tile: [kk:2][row:128][seg:4 x 16B]; slot(r,q) holds seg q^((r>>1)&3)
#define STAGE_A(bufbase, aoff) do {                                           \
    GLOAD_LDS16(A + (size_t)p_lo * 128 + (aoff) + sp * 8,                     \
                lds + (bufbase) + tid * 16);                                  \
    GLOAD_LDS16(A + (size_t)p_hi * 128 + (aoff) + sp * 8,                     \
                lds + (bufbase) + 4096 + tid * 16);                           \
    GLOAD_LDS16(A + (size_t)p_lo * 128 + (aoff) + 32 + sp * 8,                \
                lds + (bufbase) + 8192 + tid * 16);                           \
    GLOAD_LDS16(A + (size_t)p_hi * 128 + (aoff) + 32 + sp * 8,                \
                lds + (bufbase) + 8192 + 4096 + tid * 16);                    \
  } while (0)

  const int lane = tid & 63;
  const int wn = tid >> 6;
  const int l15 = lane & 15, s = lane >> 4;
  const int rdoff = l15 * 64 + ((s ^ ((l15 >> 1) & 3)) * 16);
  // B' unit index: (tau*2+kk)*1024 + (wn*4+j)*64 + lane
  const bf16x8* bB = reinterpret_cast<const bf16x8*>(Bp) + wn * 256 + lane;

#define BPRE(bb, tau) do {                                                    \
    _Pragma("unroll") for (int j = 0; j < 4; ++j) {                           \
      bb[j * 2]     = bB[(tau) * 2048 + j * 64];                              \
      bb[j * 2 + 1] = bB[(tau) * 2048 + 1024 + j * 64];                       \
    }                                                                         \
  } while (0)

  f32x4 acc[8][4];
  #pragma unroll
  for (int i = 0; i < 8; ++i)
    #pragma unroll
    for (int j = 0; j < 4; ++j)
      acc[i][j] = (f32x4){0.f, 0.f, 0.f, 0.f};

  bf16x8 b0[8], b1[8];   // index j*2+kk, all accesses compile-time

#define COMPUTE(bufbase, bb) do {                                             \
    _Pragma("unroll")                                                         \
    for (int kk = 0; kk < 2; ++kk) {                                          \
      __builtin_amdgcn_s_setprio(1);                                         \
      _Pragma("unroll")                                                       \
      for (int i = 0; i < 8; ++i) {                                           \
        bf16x8 af = *reinterpret_cast<const bf16x8*>(                         \
            lds + (bufbase) + kk * 8192 + rdoff + i * 1024);                  \
        acc[i][0] = __builtin_amdgcn_mfma_f32_16x16x32_bf16(af, bb[0 + kk],   \
                                                            acc[i][0], 0,0,0);\
        acc[i][1] = __builtin_amdgcn_mfma_f32_16x16x32_bf16(af, bb[2 + kk],   \
                                                            acc[i][1], 0,0,0);\
        acc[i][2] = __builtin_amdgcn_mfma_f32_16x16x32_bf16(af, bb[4 + kk],   \
                                                            acc[i][2], 0,0,0);\
        acc[i][3] = __builtin_amdgcn_mfma_f32_16x16x32_bf16(af, bb[6 + kk],   \
                                                            acc[i][3], 0,0,0);\
      }                                                                       \
      __builtin_amdgcn_s_setprio(0);                                         \
    }                                                                         \
  } while (0)

  // vmcnt BEFORE barrier: each wave's own A-stages retired, then all waves
  // rendezvous -> staged LDS visible block-wide.
#define FENCE() do {                                                          \
    asm volatile("s_waitcnt vmcnt(20)" ::: "memory");                         \
    __builtin_amdgcn_sched_barrier(0);                                        \
    __builtin_amdgcn_s_barrier();                                             \
  } while (0)

  // aoff(tau) = ((kh*64+kw)*128) + (tau&1)*64, tap = tau>>1
#define AOFF(tau, dst) do {                                                   \
    int _tap = (tau) >> 1; int _kh = (_tap * 11) >> 5; int _kw = _tap - _kh * 3; \
    dst = (_kh * 64 + _kw) * 128 + ((tau) & 1) * 64;                          \
  } while (0)

  // ---- prologue: tile 0 ----
  STAGE_A(0, 0);
  BPRE(b0, 0);

  #pragma unroll 1
  for (int t = 0; t < 9; ++t) {
    const int t1 = 2 * t + 1;
    const int t2 = (2 * t + 2 > 17) ? 17 : (2 * t + 2);   // K-tail clamp
    int aoff1, aoff2;
    AOFF(t1, aoff1); AOFF(t2, aoff2);

    // even phase: compute tile 2t (buf0/b0), prefetch tile t1 -> buf1/b1
    STAGE_A(16384, aoff1);
    BPRE(b1, t1);
    FENCE();
    COMPUTE(0, b0);
    __builtin_amdgcn_s_barrier();

    // odd phase: compute tile t1 (buf1/b1), prefetch tile t2 -> buf0/b0
    // (t=8: clamped duplicate of tile 17 keeps the fence count; never read)
    STAGE_A(0, aoff2);
    BPRE(b0, t2);
    FENCE();
    COMPUTE(16384, b1);
    __builtin_amdgcn_s_barrier();
  }

  // ---- epilogue: bias + fp32 store; C/D: col=lane&15, row=(lane>>4)*4+r ----
  const int colb = wn * 64 + l15;
  const int rb = bm * 128 + s * 4;
  #pragma unroll
  for (int j = 0; j < 4; ++j) {
    const float bv = bias[colb + j * 16];
    #pragma unroll
    for (int i = 0; i < 8; ++i) {
      #pragma unroll
      for (int r = 0; r < 4; ++r)
        out[(size_t)(rb + i * 16 + r) * 256 + colb + j * 16] = acc[i][j][r] + bv;
    }
  }
}

extern "C" void kernel_launch(void* const* d_in, const int* in_sizes, int n_in,
                              void* d_out, int out_size, void* d_ws, size_t ws_size,
                              hipStream_t stream) {
  const float* inp = (const float*)d_in[0];   // (32,64,64,128) fp32
  const float* w   = (const float*)d_in[1];   // (256,1152) fp32
  const float* b   = (const float*)d_in[2];   // (256) fp32
  float* out = (float*)d_out;                 // (123008,256) fp32

  unsigned short* wsA = (unsigned short*)d_ws;          // bf16 input copy
  unsigned short* wsB = wsA + 16777216;                 // bf16 fragment-major B'

  cvt_f32_bf16<<<2048, 256, 0, stream>>>(inp, wsA, 16777216 / 4);
  prep_B<<<144, 256, 0, stream>>>(w, wsB);
  conv_gemm<<<961, 256, 0, stream>>>(wsA, wsB, b, out);
}